// Round 1
// baseline (787.920 us; speedup 1.0000x reference)
//
#include <hip/hip_runtime.h>
#include <math.h>

#define BATCH 16
#define LSEQ 4096
#define DMODEL 256
#define NST 16
#define LC 128
#define NCHUNK (LSEQ / LC)
#define MROWS (BATCH * LSEQ)

__device__ __forceinline__ float silu_f(float v) { return v / (1.f + __expf(-v)); }
__device__ __forceinline__ float softplus_f(float v) {
  return fmaxf(v, 0.f) + log1pf(__expf(-fabsf(v)));
}

// ---------------------------------------------------------------------------
// GEMM: C[M,Nc] = A[M,K] @ B[Nc,K]^T (+ bias, epilogue per MODE)
// MODE 0: Nc=512, cols [0,256)->out0 (x_in), [256,512)->out1 (z), +bias
// MODE 1: Nc=256, softplus(v+bias) -> out0 (delta)
// MODE 2: Nc=32, rows<16 from B0 (W_B), rows>=16 from B1 (W_C), no bias -> out0
// MODE 3: Nc=256, v+bias -> out0 (final output)
// BM=64, BK=32, TM=4, 256 threads, 4x4 (or 4x2) register tile.
// ---------------------------------------------------------------------------
template <int BN, int TN, int MODE>
__global__ __launch_bounds__(256) void gemm_k(
    const float* __restrict__ A, const float* __restrict__ B0,
    const float* __restrict__ B1, const float* __restrict__ bias,
    float* __restrict__ out0, float* __restrict__ out1, int K) {
  constexpr int BM = 64, BK = 32, TM = 4;
  __shared__ float As[BK][BM + 4];  // +4 keeps rows 16B-aligned, bank-spread
  __shared__ float Bs[BK][BN + 4];
  const int tid = threadIdx.x;
  const int M0 = blockIdx.x * BM;
  const int N0 = blockIdx.y * BN;

  float acc[TM][TN];
#pragma unroll
  for (int i = 0; i < TM; ++i)
#pragma unroll
    for (int j = 0; j < TN; ++j) acc[i][j] = 0.f;

  const int tmb = (tid >> 4) * TM;  // 0..60
  const int tnb = (tid & 15) * TN;  // 0..(BN-TN)

  for (int k0 = 0; k0 < K; k0 += BK) {
    // stage A tile (BM x BK), transposed into As[k][m]
    constexpr int A_ITERS = (BM * BK) / (256 * 4);
#pragma unroll
    for (int i = 0; i < A_ITERS; ++i) {
      int t = tid + i * 256;
      int r = t >> 3;  // BK/4 = 8 float4 per row
      int q = t & 7;
      float4 v = *(const float4*)(A + (size_t)(M0 + r) * K + k0 + q * 4);
      As[q * 4 + 0][r] = v.x;
      As[q * 4 + 1][r] = v.y;
      As[q * 4 + 2][r] = v.z;
      As[q * 4 + 3][r] = v.w;
    }
    // stage B tile (BN x BK), transposed into Bs[k][n]
    constexpr int B_ITERS = (BN * BK) / (256 * 4);
#pragma unroll
    for (int i = 0; i < B_ITERS; ++i) {
      int t = tid + i * 256;
      int r = t >> 3;
      int q = t & 7;
      const float* Bp;
      if constexpr (MODE == 2) {
        int grow = N0 + r;
        Bp = (grow < NST) ? (B0 + (size_t)grow * K)
                          : (B1 + (size_t)(grow - NST) * K);
      } else {
        Bp = B0 + (size_t)(N0 + r) * K;
      }
      float4 v = *(const float4*)(Bp + k0 + q * 4);
      Bs[q * 4 + 0][r] = v.x;
      Bs[q * 4 + 1][r] = v.y;
      Bs[q * 4 + 2][r] = v.z;
      Bs[q * 4 + 3][r] = v.w;
    }
    __syncthreads();

#pragma unroll
    for (int k = 0; k < BK; ++k) {
      float4 av = *(const float4*)&As[k][tmb];
      float a[TM] = {av.x, av.y, av.z, av.w};
      float b[TN];
      if constexpr (TN == 4) {
        float4 bv = *(const float4*)&Bs[k][tnb];
        b[0] = bv.x; b[1] = bv.y; b[2] = bv.z; b[3] = bv.w;
      } else {
        float2 bv = *(const float2*)&Bs[k][tnb];
        b[0] = bv.x; b[1] = bv.y;
      }
#pragma unroll
      for (int i = 0; i < TM; ++i)
#pragma unroll
        for (int j = 0; j < TN; ++j) acc[i][j] = fmaf(a[i], b[j], acc[i][j]);
    }
    __syncthreads();
  }

  // epilogue
#pragma unroll
  for (int i = 0; i < TM; ++i) {
    int row = M0 + tmb + i;
    int col = N0 + tnb;
    if constexpr (MODE == 0) {
      float4 v = {acc[i][0] + bias[col + 0], acc[i][1] + bias[col + 1],
                  acc[i][2] + bias[col + 2], acc[i][3] + bias[col + 3]};
      if (col < DMODEL)
        *(float4*)(out0 + (size_t)row * DMODEL + col) = v;
      else
        *(float4*)(out1 + (size_t)row * DMODEL + (col - DMODEL)) = v;
    } else if constexpr (MODE == 1) {
      float4 v = {softplus_f(acc[i][0] + bias[col + 0]),
                  softplus_f(acc[i][1] + bias[col + 1]),
                  softplus_f(acc[i][2] + bias[col + 2]),
                  softplus_f(acc[i][3] + bias[col + 3])};
      *(float4*)(out0 + (size_t)row * DMODEL + col) = v;
    } else if constexpr (MODE == 2) {
      float2 v = {acc[i][0], acc[i][1]};
      *(float2*)(out0 + (size_t)row * 32 + col) = v;
    } else {
      float4 v = {acc[i][0] + bias[col + 0], acc[i][1] + bias[col + 1],
                  acc[i][2] + bias[col + 2], acc[i][3] + bias[col + 3]};
      *(float4*)(out0 + (size_t)row * DMODEL + col) = v;
    }
  }
}

// ---------------------------------------------------------------------------
// Depthwise conv (k=3, pad=1) over time + bias + silu.
// Block: 256 threads handle 4 consecutive l for one b (4 x 256 d).
// ---------------------------------------------------------------------------
__global__ __launch_bounds__(256) void conv_silu_k(
    const float* __restrict__ xin, const float* __restrict__ conv_w,
    const float* __restrict__ conv_b, float* __restrict__ xc) {
  __shared__ float w0[DMODEL], w1[DMODEL], w2[DMODEL], cb[DMODEL];
  const int tid = threadIdx.x;
  w0[tid] = conv_w[tid * 3 + 0];
  w1[tid] = conv_w[tid * 3 + 1];
  w2[tid] = conv_w[tid * 3 + 2];
  cb[tid] = conv_b[tid];
  __syncthreads();

  const int blk = blockIdx.x;
  const int b = blk / (LSEQ / 4);
  const int lq = blk % (LSEQ / 4);
  const int l = lq * 4 + (tid >> 6);
  const int d4 = (tid & 63) * 4;
  const size_t base = ((size_t)b * LSEQ + l) * DMODEL + d4;

  float4 zf = {0.f, 0.f, 0.f, 0.f};
  float4 xm = (l > 0) ? *(const float4*)(xin + base - DMODEL) : zf;
  float4 x0 = *(const float4*)(xin + base);
  float4 xp = (l < LSEQ - 1) ? *(const float4*)(xin + base + DMODEL) : zf;

  float o0 = fmaf(w0[d4 + 0], xm.x, fmaf(w1[d4 + 0], x0.x, fmaf(w2[d4 + 0], xp.x, cb[d4 + 0])));
  float o1 = fmaf(w0[d4 + 1], xm.y, fmaf(w1[d4 + 1], x0.y, fmaf(w2[d4 + 1], xp.y, cb[d4 + 1])));
  float o2 = fmaf(w0[d4 + 2], xm.z, fmaf(w1[d4 + 2], x0.z, fmaf(w2[d4 + 2], xp.z, cb[d4 + 2])));
  float o3 = fmaf(w0[d4 + 3], xm.w, fmaf(w1[d4 + 3], x0.w, fmaf(w2[d4 + 3], xp.w, cb[d4 + 3])));
  float4 r = {silu_f(o0), silu_f(o1), silu_f(o2), silu_f(o3)};
  *(float4*)(xc + base) = r;
}

// ---------------------------------------------------------------------------
// Scan pass 1: per (b, chunk) block, 256 threads (one per d).
// Computes h_out (h_in = 0) and cumA = exp(A * sum(dt)) per chunk.
// ---------------------------------------------------------------------------
__global__ __launch_bounds__(256) void scan_pass1(
    const float* __restrict__ delta, const float* __restrict__ xc,
    const float* __restrict__ bc, const float* __restrict__ A_log,
    float* __restrict__ hout, float* __restrict__ cumA) {
  __shared__ float Bsl[LC][NST];
  const int tid = threadIdx.x;
  const int b = blockIdx.x / NCHUNK;
  const int c = blockIdx.x % NCHUNK;
  const int l0 = c * LC;

#pragma unroll
  for (int i = 0; i < 2; ++i) {  // LC*NST = 2048 floats = 512 float4
    int t = tid + i * 256;
    int r = t >> 2;
    int q = t & 3;
    float4 v = *(const float4*)(bc + ((size_t)(b * LSEQ + l0 + r)) * 32 + q * 4);
    *(float4*)&Bsl[r][q * 4] = v;
  }
  float Aa[NST];
#pragma unroll
  for (int q = 0; q < 4; ++q) {
    float4 v = *(const float4*)(A_log + tid * NST + q * 4);
    Aa[q * 4 + 0] = -__expf(v.x);
    Aa[q * 4 + 1] = -__expf(v.y);
    Aa[q * 4 + 2] = -__expf(v.z);
    Aa[q * 4 + 3] = -__expf(v.w);
  }
  __syncthreads();

  float h[NST];
#pragma unroll
  for (int n = 0; n < NST; ++n) h[n] = 0.f;
  float sdt = 0.f;

  const size_t base = ((size_t)b * LSEQ + l0) * DMODEL + tid;
  for (int l = 0; l < LC; ++l) {
    size_t idx = base + (size_t)l * DMODEL;
    float dt = delta[idx];
    float u = xc[idx];
    sdt += dt;
    float dtu = dt * u;
#pragma unroll
    for (int n = 0; n < NST; ++n) {
      float ab = __expf(dt * Aa[n]);
      h[n] = fmaf(ab, h[n], dtu * Bsl[l][n]);
    }
  }

  const size_t ob = (((size_t)(b * NCHUNK + c)) * DMODEL + tid) * NST;
#pragma unroll
  for (int q = 0; q < 4; ++q) {
    float4 hv = {h[q * 4 + 0], h[q * 4 + 1], h[q * 4 + 2], h[q * 4 + 3]};
    *(float4*)(hout + ob + q * 4) = hv;
    float4 cv = {__expf(sdt * Aa[q * 4 + 0]), __expf(sdt * Aa[q * 4 + 1]),
                 __expf(sdt * Aa[q * 4 + 2]), __expf(sdt * Aa[q * 4 + 3])};
    *(float4*)(cumA + ob + q * 4) = cv;
  }
}

// ---------------------------------------------------------------------------
// Scan pass 2: sequential combine over chunks; one thread per (b,d,n).
// ---------------------------------------------------------------------------
__global__ __launch_bounds__(256) void scan_combine(
    const float* __restrict__ hout, const float* __restrict__ cumA,
    float* __restrict__ hin) {
  const int t = blockIdx.x * 256 + threadIdx.x;  // 65536 threads
  const int n = t & (NST - 1);
  const int d = (t / NST) & (DMODEL - 1);
  const int b = t / (NST * DMODEL);
  float h = 0.f;
  for (int c = 0; c < NCHUNK; ++c) {
    size_t idx = (((size_t)(b * NCHUNK + c)) * DMODEL + d) * NST + n;
    hin[idx] = h;
    h = fmaf(cumA[idx], h, hout[idx]);
  }
}

// ---------------------------------------------------------------------------
// Scan pass 3: replay chunk with correct h_in, produce
// y_pre = (y_ssm + xc*D_skip) * silu(z), overwriting z in-place.
// ---------------------------------------------------------------------------
__global__ __launch_bounds__(256) void scan_pass3(
    const float* __restrict__ delta, const float* __restrict__ xc,
    const float* __restrict__ bc, const float* __restrict__ A_log,
    const float* __restrict__ hin, const float* __restrict__ Dskip,
    float* __restrict__ zy) {
  __shared__ float BCs[LC][32];
  const int tid = threadIdx.x;
  const int b = blockIdx.x / NCHUNK;
  const int c = blockIdx.x % NCHUNK;
  const int l0 = c * LC;

#pragma unroll
  for (int i = 0; i < 4; ++i) {  // LC*32 = 4096 floats = 1024 float4
    int t = tid + i * 256;
    int r = t >> 3;
    int q = t & 7;
    float4 v = *(const float4*)(bc + ((size_t)(b * LSEQ + l0 + r)) * 32 + q * 4);
    *(float4*)&BCs[r][q * 4] = v;
  }
  float Aa[NST];
#pragma unroll
  for (int q = 0; q < 4; ++q) {
    float4 v = *(const float4*)(A_log + tid * NST + q * 4);
    Aa[q * 4 + 0] = -__expf(v.x);
    Aa[q * 4 + 1] = -__expf(v.y);
    Aa[q * 4 + 2] = -__expf(v.z);
    Aa[q * 4 + 3] = -__expf(v.w);
  }
  float h[NST];
  const size_t hb = (((size_t)(b * NCHUNK + c)) * DMODEL + tid) * NST;
#pragma unroll
  for (int q = 0; q < 4; ++q) {
    float4 v = *(const float4*)(hin + hb + q * 4);
    h[q * 4 + 0] = v.x;
    h[q * 4 + 1] = v.y;
    h[q * 4 + 2] = v.z;
    h[q * 4 + 3] = v.w;
  }
  const float dsk = Dskip[tid];
  __syncthreads();

  const size_t base = ((size_t)b * LSEQ + l0) * DMODEL + tid;
  for (int l = 0; l < LC; ++l) {
    size_t idx = base + (size_t)l * DMODEL;
    float dt = delta[idx];
    float u = xc[idx];
    float dtu = dt * u;
    float y = 0.f;
#pragma unroll
    for (int n = 0; n < NST; ++n) {
      float ab = __expf(dt * Aa[n]);
      h[n] = fmaf(ab, h[n], dtu * BCs[l][n]);
      y = fmaf(h[n], BCs[l][NST + n], y);
    }
    float zv = zy[idx];
    zy[idx] = (y + u * dsk) * silu_f(zv);
  }
}

// ---------------------------------------------------------------------------
extern "C" void kernel_launch(void* const* d_in, const int* in_sizes, int n_in,
                              void* d_out, int out_size, void* d_ws,
                              size_t ws_size, hipStream_t stream) {
  const float* x       = (const float*)d_in[0];
  const float* A_log   = (const float*)d_in[1];
  const float* D_skip  = (const float*)d_in[2];
  const float* W_B     = (const float*)d_in[3];
  const float* W_C     = (const float*)d_in[4];
  const float* W_delta = (const float*)d_in[5];
  const float* b_delta = (const float*)d_in[6];
  const float* W_in    = (const float*)d_in[7];
  const float* b_in    = (const float*)d_in[8];
  const float* W_out   = (const float*)d_in[9];
  const float* b_out   = (const float*)d_in[10];
  const float* conv_w  = (const float*)d_in[11];
  const float* conv_b  = (const float*)d_in[12];

  float* ws = (float*)d_ws;
  const size_t MD = (size_t)MROWS * DMODEL;          // 16777216
  const size_t HP = (size_t)BATCH * NCHUNK * DMODEL * NST;  // 2097152
  float* xin  = ws;            // x_in; reused as delta after conv
  float* zy   = xin + MD;      // z; reused as y_pre by pass3
  float* xc   = zy + MD;
  float* bc   = xc + MD;       // [M,32]: cols 0..15 B_sel, 16..31 C_sel
  float* hout = bc + (size_t)MROWS * 32;
  float* cumA = hout + HP;
  float* hin  = cumA + HP;

  // 1) xz = x @ W_in.T + b_in -> x_in, z
  gemm_k<64, 4, 0><<<dim3(MROWS / 64, 8), 256, 0, stream>>>(
      x, W_in, nullptr, b_in, xin, zy, DMODEL);
  // 2) depthwise conv + silu -> xc
  conv_silu_k<<<dim3(BATCH * LSEQ / 4), 256, 0, stream>>>(xin, conv_w, conv_b, xc);
  // 3) delta = softplus(xc @ W_delta.T + b_delta) -> xin (reuse)
  gemm_k<64, 4, 1><<<dim3(MROWS / 64, 4), 256, 0, stream>>>(
      xc, W_delta, nullptr, b_delta, xin, nullptr, DMODEL);
  // 4) B_sel/C_sel = xc @ [W_B;W_C].T -> bc
  gemm_k<32, 2, 2><<<dim3(MROWS / 64, 1), 256, 0, stream>>>(
      xc, W_B, W_C, nullptr, bc, nullptr, DMODEL);
  // 5) chunked scan
  scan_pass1<<<dim3(BATCH * NCHUNK), 256, 0, stream>>>(xin, xc, bc, A_log, hout, cumA);
  scan_combine<<<dim3(BATCH * DMODEL * NST / 256), 256, 0, stream>>>(hout, cumA, hin);
  scan_pass3<<<dim3(BATCH * NCHUNK), 256, 0, stream>>>(xin, xc, bc, A_log, hin, D_skip, zy);
  // 6) out = y_pre @ W_out.T + b_out
  gemm_k<64, 4, 3><<<dim3(MROWS / 64, 4), 256, 0, stream>>>(
      zy, W_out, nullptr, b_out, (float*)d_out, nullptr, DMODEL);
}

// Round 2
// 389.849 us; speedup vs baseline: 2.0211x; 2.0211x over previous
//
#include <hip/hip_runtime.h>
#include <hip/hip_bf16.h>
#include <math.h>

#define BATCH 16
#define LSEQ 4096
#define DMODEL 256
#define NST 16
#define LC 128
#define NCHUNK (LSEQ / LC)
#define MROWS (BATCH * LSEQ)

typedef float f32x4 __attribute__((ext_vector_type(4)));
typedef short bf16x8 __attribute__((ext_vector_type(8)));

__device__ __forceinline__ float silu_f(float v) { return v / (1.f + __expf(-v)); }
__device__ __forceinline__ float softplus_f(float v) {
  return fmaxf(v, 0.f) + log1pf(__expf(-fabsf(v)));
}

// fp32 -> bf16 round-to-nearest-even (finite inputs), packed pair
__device__ __forceinline__ uint bf16rne(float f) {
  uint u = __float_as_uint(f);
  return (u + 0x7fffu + ((u >> 16) & 1u)) >> 16;
}
__device__ __forceinline__ uint pk2(float x, float y) {
  return bf16rne(x) | (bf16rne(y) << 16);
}
__device__ __forceinline__ uint4 pk8(float4 a, float4 b) {
  uint4 r;
  r.x = pk2(a.x, a.y);
  r.y = pk2(a.z, a.w);
  r.z = pk2(b.x, b.y);
  r.w = pk2(b.z, b.w);
  return r;
}

// ---------------------------------------------------------------------------
// MFMA GEMM: out[M,N] = A[M,K=256] @ B[N,K]^T (+bias, epilogue per MODE)
// Block tile 128 x 256, BK=32, 8 waves (512 thr), per-wave 64x64 (4x4 frags).
// MODE 0: N=512 via gridDim.x=2; cols<256 -> out0 (x_in), >=256 -> out1 (z)
// MODE 1: softplus(v+bias) -> out0 (delta)
// MODE 3: v+bias -> out0 (final)
// LDS rows are 32 bf16 (4 x 16B chunks), XOR-swizzled chunk^(row&3).
// ---------------------------------------------------------------------------
template <int MODE>
__global__ __launch_bounds__(512, 4) void mfma_main(
    const float* __restrict__ A, const float* __restrict__ B,
    const float* __restrict__ bias, float* __restrict__ out0,
    float* __restrict__ out1) {
  constexpr int K = DMODEL;
  __shared__ uint4 lsA[128 * 4];  // 8 KB
  __shared__ uint4 lsB[256 * 4];  // 16 KB
  const int tid = threadIdx.x;
  const int lane = tid & 63, wid = tid >> 6;
  const int wr = wid >> 2, wc = wid & 3;

  // dispatch swizzle: logical pairs (2m,2m+1) land on the same XCD
  int d = blockIdx.y * gridDim.x + blockIdx.x;
  int lg = (d & ~15) | ((d & 7) << 1) | ((d >> 3) & 1);
  const int bx = lg % gridDim.x;
  const int by = lg / gridDim.x;
  const int M0 = by * 128, N0 = bx * 256;

  f32x4 acc[4][4];
#pragma unroll
  for (int i = 0; i < 4; ++i)
#pragma unroll
    for (int j = 0; j < 4; ++j) acc[i][j] = {0.f, 0.f, 0.f, 0.f};

  const int ar = tid >> 2, aq = tid & 3;  // A: 128 rows, 8 fp32/thread
  const int br = tid >> 1, bh = tid & 1;  // B: 256 rows, 16 fp32/thread
  const float* gA = A + (size_t)(M0 + ar) * K + aq * 8;
  const float* gB = B + (size_t)(N0 + br) * K + bh * 16;

  for (int k0 = 0; k0 < K; k0 += 32) {
    float4 a0 = *(const float4*)(gA + k0);
    float4 a1 = *(const float4*)(gA + k0 + 4);
    float4 b0 = *(const float4*)(gB + k0);
    float4 b1 = *(const float4*)(gB + k0 + 4);
    float4 b2 = *(const float4*)(gB + k0 + 8);
    float4 b3 = *(const float4*)(gB + k0 + 12);
    lsA[ar * 4 + (aq ^ (ar & 3))] = pk8(a0, a1);
    lsB[br * 4 + ((bh * 2) ^ (br & 3))] = pk8(b0, b1);
    lsB[br * 4 + ((bh * 2 + 1) ^ (br & 3))] = pk8(b2, b3);
    __syncthreads();

    bf16x8 af[4], bfr[4];
#pragma unroll
    for (int i = 0; i < 4; ++i) {
      int r = wr * 64 + i * 16 + (lane & 15);
      af[i] = *(const bf16x8*)&lsA[r * 4 + ((lane >> 4) ^ (r & 3))];
    }
#pragma unroll
    for (int j = 0; j < 4; ++j) {
      int r = wc * 64 + j * 16 + (lane & 15);
      bfr[j] = *(const bf16x8*)&lsB[r * 4 + ((lane >> 4) ^ (r & 3))];
    }
#pragma unroll
    for (int i = 0; i < 4; ++i)
#pragma unroll
      for (int j = 0; j < 4; ++j)
        acc[i][j] = __builtin_amdgcn_mfma_f32_16x16x32_bf16(af[i], bfr[j],
                                                            acc[i][j], 0, 0, 0);
    __syncthreads();
  }

  const int rbase = (lane >> 4) * 4;
  const int cn = lane & 15;
#pragma unroll
  for (int i = 0; i < 4; ++i) {
#pragma unroll
    for (int j = 0; j < 4; ++j) {
      int col = N0 + wc * 64 + j * 16 + cn;
      float bs = bias[col];
#pragma unroll
      for (int r = 0; r < 4; ++r) {
        int row = M0 + wr * 64 + i * 16 + rbase + r;
        float v = acc[i][j][r] + bs;
        if constexpr (MODE == 1) v = softplus_f(v);
        if constexpr (MODE == 0) {
          if (col < DMODEL)
            out0[(size_t)row * DMODEL + col] = v;
          else
            out1[(size_t)row * DMODEL + (col - DMODEL)] = v;
        } else {
          out0[(size_t)row * DMODEL + col] = v;
        }
      }
    }
  }
}

// ---------------------------------------------------------------------------
// MFMA GEMM for B_sel/C_sel: out[M,32] = xc @ [W_B;W_C]^T.
// Block tile 256 x 32, BK=32, 4 waves (256 thr), per-wave 64x32 (4x2 frags).
// ---------------------------------------------------------------------------
__global__ __launch_bounds__(256, 4) void mfma_bc(
    const float* __restrict__ A, const float* __restrict__ WB,
    const float* __restrict__ WC, float* __restrict__ out0) {
  constexpr int K = DMODEL;
  __shared__ uint4 lsA[256 * 4];  // 16 KB
  __shared__ uint4 lsB[32 * 4];   // 2 KB
  const int tid = threadIdx.x;
  const int lane = tid & 63, wid = tid >> 6;
  const int M0 = blockIdx.y * 256;

  f32x4 acc[4][2];
#pragma unroll
  for (int i = 0; i < 4; ++i)
#pragma unroll
    for (int j = 0; j < 2; ++j) acc[i][j] = {0.f, 0.f, 0.f, 0.f};

  const float* gA = A + (size_t)(M0 + tid) * K;  // one row per thread
  const int brr = tid >> 2, bq = tid & 3;
  const float* gB =
      (brr < NST ? WB + (size_t)brr * K : WC + (size_t)(brr - NST) * K) + bq * 8;

  for (int k0 = 0; k0 < K; k0 += 32) {
    float4 av[8];
#pragma unroll
    for (int q = 0; q < 8; ++q) av[q] = *(const float4*)(gA + k0 + q * 4);
#pragma unroll
    for (int q = 0; q < 4; ++q)
      lsA[tid * 4 + (q ^ (tid & 3))] = pk8(av[2 * q], av[2 * q + 1]);
    if (tid < 128) {
      float4 b0 = *(const float4*)(gB + k0);
      float4 b1 = *(const float4*)(gB + k0 + 4);
      lsB[brr * 4 + (bq ^ (brr & 3))] = pk8(b0, b1);
    }
    __syncthreads();

    bf16x8 af[4], bfr[2];
#pragma unroll
    for (int i = 0; i < 4; ++i) {
      int r = wid * 64 + i * 16 + (lane & 15);
      af[i] = *(const bf16x8*)&lsA[r * 4 + ((lane >> 4) ^ (r & 3))];
    }
#pragma unroll
    for (int j = 0; j < 2; ++j) {
      int r = j * 16 + (lane & 15);
      bfr[j] = *(const bf16x8*)&lsB[r * 4 + ((lane >> 4) ^ (r & 3))];
    }
#pragma unroll
    for (int i = 0; i < 4; ++i)
#pragma unroll
      for (int j = 0; j < 2; ++j)
        acc[i][j] = __builtin_amdgcn_mfma_f32_16x16x32_bf16(af[i], bfr[j],
                                                            acc[i][j], 0, 0, 0);
    __syncthreads();
  }

  const int rbase = (lane >> 4) * 4;
  const int cn = lane & 15;
#pragma unroll
  for (int i = 0; i < 4; ++i)
#pragma unroll
    for (int j = 0; j < 2; ++j)
#pragma unroll
      for (int r = 0; r < 4; ++r) {
        int row = M0 + wid * 64 + i * 16 + rbase + r;
        out0[(size_t)row * 32 + j * 16 + cn] = acc[i][j][r];
      }
}

// ---------------------------------------------------------------------------
// Depthwise conv (k=3, pad=1) over time + bias + silu.
// ---------------------------------------------------------------------------
__global__ __launch_bounds__(256) void conv_silu_k(
    const float* __restrict__ xin, const float* __restrict__ conv_w,
    const float* __restrict__ conv_b, float* __restrict__ xc) {
  __shared__ float w0[DMODEL], w1[DMODEL], w2[DMODEL], cb[DMODEL];
  const int tid = threadIdx.x;
  w0[tid] = conv_w[tid * 3 + 0];
  w1[tid] = conv_w[tid * 3 + 1];
  w2[tid] = conv_w[tid * 3 + 2];
  cb[tid] = conv_b[tid];
  __syncthreads();

  const int blk = blockIdx.x;
  const int b = blk / (LSEQ / 4);
  const int lq = blk % (LSEQ / 4);
  const int l = lq * 4 + (tid >> 6);
  const int d4 = (tid & 63) * 4;
  const size_t base = ((size_t)b * LSEQ + l) * DMODEL + d4;

  float4 zf = {0.f, 0.f, 0.f, 0.f};
  float4 xm = (l > 0) ? *(const float4*)(xin + base - DMODEL) : zf;
  float4 x0 = *(const float4*)(xin + base);
  float4 xp = (l < LSEQ - 1) ? *(const float4*)(xin + base + DMODEL) : zf;

  float o0 = fmaf(w0[d4 + 0], xm.x, fmaf(w1[d4 + 0], x0.x, fmaf(w2[d4 + 0], xp.x, cb[d4 + 0])));
  float o1 = fmaf(w0[d4 + 1], xm.y, fmaf(w1[d4 + 1], x0.y, fmaf(w2[d4 + 1], xp.y, cb[d4 + 1])));
  float o2 = fmaf(w0[d4 + 2], xm.z, fmaf(w1[d4 + 2], x0.z, fmaf(w2[d4 + 2], xp.z, cb[d4 + 2])));
  float o3 = fmaf(w0[d4 + 3], xm.w, fmaf(w1[d4 + 3], x0.w, fmaf(w2[d4 + 3], xp.w, cb[d4 + 3])));
  float4 r = {silu_f(o0), silu_f(o1), silu_f(o2), silu_f(o3)};
  *(float4*)(xc + base) = r;
}

// ---------------------------------------------------------------------------
// Scan pass 1: per (b, chunk) block, 256 threads (one per d).
// ---------------------------------------------------------------------------
__global__ __launch_bounds__(256) void scan_pass1(
    const float* __restrict__ delta, const float* __restrict__ xc,
    const float* __restrict__ bc, const float* __restrict__ A_log,
    float* __restrict__ hout, float* __restrict__ cumA) {
  __shared__ float Bsl[LC][NST];
  const int tid = threadIdx.x;
  const int b = blockIdx.x / NCHUNK;
  const int c = blockIdx.x % NCHUNK;
  const int l0 = c * LC;

#pragma unroll
  for (int i = 0; i < 2; ++i) {
    int t = tid + i * 256;
    int r = t >> 2;
    int q = t & 3;
    float4 v = *(const float4*)(bc + ((size_t)(b * LSEQ + l0 + r)) * 32 + q * 4);
    *(float4*)&Bsl[r][q * 4] = v;
  }
  float Aa[NST];
#pragma unroll
  for (int q = 0; q < 4; ++q) {
    float4 v = *(const float4*)(A_log + tid * NST + q * 4);
    Aa[q * 4 + 0] = -__expf(v.x);
    Aa[q * 4 + 1] = -__expf(v.y);
    Aa[q * 4 + 2] = -__expf(v.z);
    Aa[q * 4 + 3] = -__expf(v.w);
  }
  __syncthreads();

  float h[NST];
#pragma unroll
  for (int n = 0; n < NST; ++n) h[n] = 0.f;
  float sdt = 0.f;

  const size_t base = ((size_t)b * LSEQ + l0) * DMODEL + tid;
  for (int l = 0; l < LC; ++l) {
    size_t idx = base + (size_t)l * DMODEL;
    float dt = delta[idx];
    float u = xc[idx];
    sdt += dt;
    float dtu = dt * u;
#pragma unroll
    for (int n = 0; n < NST; ++n) {
      float ab = __expf(dt * Aa[n]);
      h[n] = fmaf(ab, h[n], dtu * Bsl[l][n]);
    }
  }

  const size_t ob = (((size_t)(b * NCHUNK + c)) * DMODEL + tid) * NST;
#pragma unroll
  for (int q = 0; q < 4; ++q) {
    float4 hv = {h[q * 4 + 0], h[q * 4 + 1], h[q * 4 + 2], h[q * 4 + 3]};
    *(float4*)(hout + ob + q * 4) = hv;
    float4 cv = {__expf(sdt * Aa[q * 4 + 0]), __expf(sdt * Aa[q * 4 + 1]),
                 __expf(sdt * Aa[q * 4 + 2]), __expf(sdt * Aa[q * 4 + 3])};
    *(float4*)(cumA + ob + q * 4) = cv;
  }
}

// ---------------------------------------------------------------------------
// Scan pass 2: sequential combine over chunks; one thread per (b,d,n).
// ---------------------------------------------------------------------------
__global__ __launch_bounds__(256) void scan_combine(
    const float* __restrict__ hout, const float* __restrict__ cumA,
    float* __restrict__ hin) {
  const int t = blockIdx.x * 256 + threadIdx.x;
  const int n = t & (NST - 1);
  const int dd = (t / NST) & (DMODEL - 1);
  const int b = t / (NST * DMODEL);
  float h = 0.f;
  for (int c = 0; c < NCHUNK; ++c) {
    size_t idx = (((size_t)(b * NCHUNK + c)) * DMODEL + dd) * NST + n;
    hin[idx] = h;
    h = fmaf(cumA[idx], h, hout[idx]);
  }
}

// ---------------------------------------------------------------------------
// Scan pass 3: replay with correct h_in, y_pre = (y+xc*D)*silu(z) into zy.
// ---------------------------------------------------------------------------
__global__ __launch_bounds__(256) void scan_pass3(
    const float* __restrict__ delta, const float* __restrict__ xc,
    const float* __restrict__ bc, const float* __restrict__ A_log,
    const float* __restrict__ hin, const float* __restrict__ Dskip,
    float* __restrict__ zy) {
  __shared__ float BCs[LC][32];
  const int tid = threadIdx.x;
  const int b = blockIdx.x / NCHUNK;
  const int c = blockIdx.x % NCHUNK;
  const int l0 = c * LC;

#pragma unroll
  for (int i = 0; i < 4; ++i) {
    int t = tid + i * 256;
    int r = t >> 3;
    int q = t & 7;
    float4 v = *(const float4*)(bc + ((size_t)(b * LSEQ + l0 + r)) * 32 + q * 4);
    *(float4*)&BCs[r][q * 4] = v;
  }
  float Aa[NST];
#pragma unroll
  for (int q = 0; q < 4; ++q) {
    float4 v = *(const float4*)(A_log + tid * NST + q * 4);
    Aa[q * 4 + 0] = -__expf(v.x);
    Aa[q * 4 + 1] = -__expf(v.y);
    Aa[q * 4 + 2] = -__expf(v.z);
    Aa[q * 4 + 3] = -__expf(v.w);
  }
  float h[NST];
  const size_t hb = (((size_t)(b * NCHUNK + c)) * DMODEL + tid) * NST;
#pragma unroll
  for (int q = 0; q < 4; ++q) {
    float4 v = *(const float4*)(hin + hb + q * 4);
    h[q * 4 + 0] = v.x;
    h[q * 4 + 1] = v.y;
    h[q * 4 + 2] = v.z;
    h[q * 4 + 3] = v.w;
  }
  const float dsk = Dskip[tid];
  __syncthreads();

  const size_t base = ((size_t)b * LSEQ + l0) * DMODEL + tid;
  for (int l = 0; l < LC; ++l) {
    size_t idx = base + (size_t)l * DMODEL;
    float dt = delta[idx];
    float u = xc[idx];
    float dtu = dt * u;
    float y = 0.f;
#pragma unroll
    for (int n = 0; n < NST; ++n) {
      float ab = __expf(dt * Aa[n]);
      h[n] = fmaf(ab, h[n], dtu * BCs[l][n]);
      y = fmaf(h[n], BCs[l][NST + n], y);
    }
    float zv = zy[idx];
    zy[idx] = (y + u * dsk) * silu_f(zv);
  }
}

// ---------------------------------------------------------------------------
extern "C" void kernel_launch(void* const* d_in, const int* in_sizes, int n_in,
                              void* d_out, int out_size, void* d_ws,
                              size_t ws_size, hipStream_t stream) {
  const float* x       = (const float*)d_in[0];
  const float* A_log   = (const float*)d_in[1];
  const float* D_skip  = (const float*)d_in[2];
  const float* W_B     = (const float*)d_in[3];
  const float* W_C     = (const float*)d_in[4];
  const float* W_delta = (const float*)d_in[5];
  const float* b_delta = (const float*)d_in[6];
  const float* W_in    = (const float*)d_in[7];
  const float* b_in    = (const float*)d_in[8];
  const float* W_out   = (const float*)d_in[9];
  const float* b_out   = (const float*)d_in[10];
  const float* conv_w  = (const float*)d_in[11];
  const float* conv_b  = (const float*)d_in[12];

  float* ws = (float*)d_ws;
  const size_t MD = (size_t)MROWS * DMODEL;
  const size_t HP = (size_t)BATCH * NCHUNK * DMODEL * NST;
  float* xin  = ws;        // x_in; reused as delta
  float* zy   = xin + MD;  // z; reused as y_pre
  float* xc   = zy + MD;
  float* bc   = xc + MD;   // [M,32]
  float* hout = bc + (size_t)MROWS * 32;
  float* cumA = hout + HP;
  float* hin  = cumA + HP;

  // 1) xz = x @ W_in.T + b_in -> x_in, z
  mfma_main<0><<<dim3(2, MROWS / 128), 512, 0, stream>>>(x, W_in, b_in, xin, zy);
  // 2) depthwise conv + silu -> xc
  conv_silu_k<<<dim3(BATCH * LSEQ / 4), 256, 0, stream>>>(xin, conv_w, conv_b, xc);
  // 3) delta = softplus(xc @ W_delta.T + b_delta) -> xin
  mfma_main<1><<<dim3(1, MROWS / 128), 512, 0, stream>>>(xc, W_delta, b_delta, xin, nullptr);
  // 4) B_sel/C_sel -> bc
  mfma_bc<<<dim3(1, MROWS / 256), 256, 0, stream>>>(xc, W_B, W_C, bc);
  // 5) chunked scan
  scan_pass1<<<dim3(BATCH * NCHUNK), 256, 0, stream>>>(xin, xc, bc, A_log, hout, cumA);
  scan_combine<<<dim3(BATCH * DMODEL * NST / 256), 256, 0, stream>>>(hout, cumA, hin);
  scan_pass3<<<dim3(BATCH * NCHUNK), 256, 0, stream>>>(xin, xc, bc, A_log, hin, D_skip, zy);
  // 6) out = y_pre @ W_out.T + b_out
  mfma_main<3><<<dim3(1, MROWS / 128), 512, 0, stream>>>(zy, W_out, b_out, (float*)d_out, nullptr);
}

// Round 3
// 334.258 us; speedup vs baseline: 2.3572x; 1.1663x over previous
//
#include <hip/hip_runtime.h>
#include <hip/hip_bf16.h>
#include <math.h>

#define BATCH 16
#define LSEQ 4096
#define DMODEL 256
#define NST 16
#define LC 64
#define NCHUNK (LSEQ / LC)
#define MROWS (BATCH * LSEQ)
#define LOG2E 1.44269504088896340736f

typedef float f32x4 __attribute__((ext_vector_type(4)));
typedef short bf16x8 __attribute__((ext_vector_type(8)));

__device__ __forceinline__ float silu_f(float v) { return v / (1.f + __expf(-v)); }
__device__ __forceinline__ float softplus_f(float v) {
  return fmaxf(v, 0.f) + log1pf(__expf(-fabsf(v)));
}

// fp32 -> bf16 round-to-nearest-even (finite inputs), packed pair
__device__ __forceinline__ uint bf16rne(float f) {
  uint u = __float_as_uint(f);
  return (u + 0x7fffu + ((u >> 16) & 1u)) >> 16;
}
__device__ __forceinline__ uint pk2(float x, float y) {
  return bf16rne(x) | (bf16rne(y) << 16);
}
__device__ __forceinline__ uint4 pk8(float4 a, float4 b) {
  uint4 r;
  r.x = pk2(a.x, a.y);
  r.y = pk2(a.z, a.w);
  r.z = pk2(b.x, b.y);
  r.w = pk2(b.z, b.w);
  return r;
}

// ---------------------------------------------------------------------------
// MFMA GEMM: out[M,N] = A[M,K=256] @ B[N,K]^T (+bias, epilogue per MODE)
// Block tile 128 x 256, BK=32, 8 waves (512 thr), per-wave 64x64 (4x4 frags).
// MODE 0: N=512 via gridDim.x=2; cols<256 -> out0 (x_in), >=256 -> out1 (z)
// MODE 1: softplus(v+bias) -> out0 (delta)
// MODE 3: v+bias -> out0 (final)
// ---------------------------------------------------------------------------
template <int MODE>
__global__ __launch_bounds__(512, 4) void mfma_main(
    const float* __restrict__ A, const float* __restrict__ B,
    const float* __restrict__ bias, float* __restrict__ out0,
    float* __restrict__ out1) {
  constexpr int K = DMODEL;
  __shared__ uint4 lsA[128 * 4];  // 8 KB
  __shared__ uint4 lsB[256 * 4];  // 16 KB
  const int tid = threadIdx.x;
  const int lane = tid & 63, wid = tid >> 6;
  const int wr = wid >> 2, wc = wid & 3;

  // dispatch swizzle: logical pairs (2m,2m+1) land on the same XCD
  int d = blockIdx.y * gridDim.x + blockIdx.x;
  int lg = (d & ~15) | ((d & 7) << 1) | ((d >> 3) & 1);
  const int bx = lg % gridDim.x;
  const int by = lg / gridDim.x;
  const int M0 = by * 128, N0 = bx * 256;

  f32x4 acc[4][4];
#pragma unroll
  for (int i = 0; i < 4; ++i)
#pragma unroll
    for (int j = 0; j < 4; ++j) acc[i][j] = {0.f, 0.f, 0.f, 0.f};

  const int ar = tid >> 2, aq = tid & 3;  // A: 128 rows, 8 fp32/thread
  const int br = tid >> 1, bh = tid & 1;  // B: 256 rows, 16 fp32/thread
  const float* gA = A + (size_t)(M0 + ar) * K + aq * 8;
  const float* gB = B + (size_t)(N0 + br) * K + bh * 16;

  for (int k0 = 0; k0 < K; k0 += 32) {
    float4 a0 = *(const float4*)(gA + k0);
    float4 a1 = *(const float4*)(gA + k0 + 4);
    float4 b0 = *(const float4*)(gB + k0);
    float4 b1 = *(const float4*)(gB + k0 + 4);
    float4 b2 = *(const float4*)(gB + k0 + 8);
    float4 b3 = *(const float4*)(gB + k0 + 12);
    lsA[ar * 4 + (aq ^ (ar & 3))] = pk8(a0, a1);
    lsB[br * 4 + ((bh * 2) ^ (br & 3))] = pk8(b0, b1);
    lsB[br * 4 + ((bh * 2 + 1) ^ (br & 3))] = pk8(b2, b3);
    __syncthreads();

    bf16x8 af[4], bfr[4];
#pragma unroll
    for (int i = 0; i < 4; ++i) {
      int r = wr * 64 + i * 16 + (lane & 15);
      af[i] = *(const bf16x8*)&lsA[r * 4 + ((lane >> 4) ^ (r & 3))];
    }
#pragma unroll
    for (int j = 0; j < 4; ++j) {
      int r = wc * 64 + j * 16 + (lane & 15);
      bfr[j] = *(const bf16x8*)&lsB[r * 4 + ((lane >> 4) ^ (r & 3))];
    }
#pragma unroll
    for (int i = 0; i < 4; ++i)
#pragma unroll
      for (int j = 0; j < 4; ++j)
        acc[i][j] = __builtin_amdgcn_mfma_f32_16x16x32_bf16(af[i], bfr[j],
                                                            acc[i][j], 0, 0, 0);
    __syncthreads();
  }

  const int rbase = (lane >> 4) * 4;
  const int cn = lane & 15;
#pragma unroll
  for (int i = 0; i < 4; ++i) {
#pragma unroll
    for (int j = 0; j < 4; ++j) {
      int col = N0 + wc * 64 + j * 16 + cn;
      float bs = bias[col];
#pragma unroll
      for (int r = 0; r < 4; ++r) {
        int row = M0 + wr * 64 + i * 16 + rbase + r;
        float v = acc[i][j][r] + bs;
        if constexpr (MODE == 1) v = softplus_f(v);
        if constexpr (MODE == 0) {
          if (col < DMODEL)
            out0[(size_t)row * DMODEL + col] = v;
          else
            out1[(size_t)row * DMODEL + (col - DMODEL)] = v;
        } else {
          out0[(size_t)row * DMODEL + col] = v;
        }
      }
    }
  }
}

// ---------------------------------------------------------------------------
// MFMA GEMM for B_sel/C_sel: out[M,32] = xc @ [W_B;W_C]^T.
// ---------------------------------------------------------------------------
__global__ __launch_bounds__(256, 4) void mfma_bc(
    const float* __restrict__ A, const float* __restrict__ WB,
    const float* __restrict__ WC, float* __restrict__ out0) {
  constexpr int K = DMODEL;
  __shared__ uint4 lsA[256 * 4];  // 16 KB
  __shared__ uint4 lsB[32 * 4];   // 2 KB
  const int tid = threadIdx.x;
  const int lane = tid & 63, wid = tid >> 6;
  const int M0 = blockIdx.y * 256;

  f32x4 acc[4][2];
#pragma unroll
  for (int i = 0; i < 4; ++i)
#pragma unroll
    for (int j = 0; j < 2; ++j) acc[i][j] = {0.f, 0.f, 0.f, 0.f};

  const float* gA = A + (size_t)(M0 + tid) * K;
  const int brr = tid >> 2, bq = tid & 3;
  const float* gB =
      (brr < NST ? WB + (size_t)brr * K : WC + (size_t)(brr - NST) * K) + bq * 8;

  for (int k0 = 0; k0 < K; k0 += 32) {
    float4 av[8];
#pragma unroll
    for (int q = 0; q < 8; ++q) av[q] = *(const float4*)(gA + k0 + q * 4);
#pragma unroll
    for (int q = 0; q < 4; ++q)
      lsA[tid * 4 + (q ^ (tid & 3))] = pk8(av[2 * q], av[2 * q + 1]);
    if (tid < 128) {
      float4 b0 = *(const float4*)(gB + k0);
      float4 b1 = *(const float4*)(gB + k0 + 4);
      lsB[brr * 4 + (bq ^ (brr & 3))] = pk8(b0, b1);
    }
    __syncthreads();

    bf16x8 af[4], bfr[2];
#pragma unroll
    for (int i = 0; i < 4; ++i) {
      int r = wid * 64 + i * 16 + (lane & 15);
      af[i] = *(const bf16x8*)&lsA[r * 4 + ((lane >> 4) ^ (r & 3))];
    }
#pragma unroll
    for (int j = 0; j < 2; ++j) {
      int r = j * 16 + (lane & 15);
      bfr[j] = *(const bf16x8*)&lsB[r * 4 + ((lane >> 4) ^ (r & 3))];
    }
#pragma unroll
    for (int i = 0; i < 4; ++i)
#pragma unroll
      for (int j = 0; j < 2; ++j)
        acc[i][j] = __builtin_amdgcn_mfma_f32_16x16x32_bf16(af[i], bfr[j],
                                                            acc[i][j], 0, 0, 0);
    __syncthreads();
  }

  const int rbase = (lane >> 4) * 4;
  const int cn = lane & 15;
#pragma unroll
  for (int i = 0; i < 4; ++i)
#pragma unroll
    for (int j = 0; j < 2; ++j)
#pragma unroll
      for (int r = 0; r < 4; ++r) {
        int row = M0 + wid * 64 + i * 16 + rbase + r;
        out0[(size_t)row * 32 + j * 16 + cn] = acc[i][j][r];
      }
}

// ---------------------------------------------------------------------------
// Depthwise conv (k=3, pad=1) over time + bias + silu.
// ---------------------------------------------------------------------------
__global__ __launch_bounds__(256) void conv_silu_k(
    const float* __restrict__ xin, const float* __restrict__ conv_w,
    const float* __restrict__ conv_b, float* __restrict__ xc) {
  __shared__ float w0[DMODEL], w1[DMODEL], w2[DMODEL], cb[DMODEL];
  const int tid = threadIdx.x;
  w0[tid] = conv_w[tid * 3 + 0];
  w1[tid] = conv_w[tid * 3 + 1];
  w2[tid] = conv_w[tid * 3 + 2];
  cb[tid] = conv_b[tid];
  __syncthreads();

  const int blk = blockIdx.x;
  const int b = blk / (LSEQ / 4);
  const int lq = blk % (LSEQ / 4);
  const int l = lq * 4 + (tid >> 6);
  const int d4 = (tid & 63) * 4;
  const size_t base = ((size_t)b * LSEQ + l) * DMODEL + d4;

  float4 zf = {0.f, 0.f, 0.f, 0.f};
  float4 xm = (l > 0) ? *(const float4*)(xin + base - DMODEL) : zf;
  float4 x0 = *(const float4*)(xin + base);
  float4 xp = (l < LSEQ - 1) ? *(const float4*)(xin + base + DMODEL) : zf;

  float o0 = fmaf(w0[d4 + 0], xm.x, fmaf(w1[d4 + 0], x0.x, fmaf(w2[d4 + 0], xp.x, cb[d4 + 0])));
  float o1 = fmaf(w0[d4 + 1], xm.y, fmaf(w1[d4 + 1], x0.y, fmaf(w2[d4 + 1], xp.y, cb[d4 + 1])));
  float o2 = fmaf(w0[d4 + 2], xm.z, fmaf(w1[d4 + 2], x0.z, fmaf(w2[d4 + 2], xp.z, cb[d4 + 2])));
  float o3 = fmaf(w0[d4 + 3], xm.w, fmaf(w1[d4 + 3], x0.w, fmaf(w2[d4 + 3], xp.w, cb[d4 + 3])));
  float4 r = {silu_f(o0), silu_f(o1), silu_f(o2), silu_f(o3)};
  *(float4*)(xc + base) = r;
}

// ---------------------------------------------------------------------------
// Scan pass 1: per (b, chunk) block, 256 threads (one per d), LC=64.
// h_out with h_in=0, cumA = exp2(sum(dt) * Aa2). Register double-buffered
// unroll-4 l-loop for memory-latency hiding.
// ---------------------------------------------------------------------------
__global__ __launch_bounds__(256) void scan_pass1(
    const float* __restrict__ delta, const float* __restrict__ xc,
    const float* __restrict__ bc, const float* __restrict__ A_log,
    float* __restrict__ hout, float* __restrict__ cumA) {
  __shared__ float Bsl[LC][NST];  // 4 KB
  const int tid = threadIdx.x;
  const int b = blockIdx.x / NCHUNK;
  const int c = blockIdx.x % NCHUNK;
  const int l0 = c * LC;

  {  // LC*NST = 1024 floats = 256 float4, one per thread
    int r = tid >> 2, q = tid & 3;
    float4 v = *(const float4*)(bc + ((size_t)(b * LSEQ + l0 + r)) * 32 + q * 4);
    *(float4*)&Bsl[r][q * 4] = v;
  }
  float Aa2[NST];  // -exp(A_log) * log2(e)
#pragma unroll
  for (int q = 0; q < 4; ++q) {
    float4 v = *(const float4*)(A_log + tid * NST + q * 4);
    Aa2[q * 4 + 0] = -LOG2E * __expf(v.x);
    Aa2[q * 4 + 1] = -LOG2E * __expf(v.y);
    Aa2[q * 4 + 2] = -LOG2E * __expf(v.z);
    Aa2[q * 4 + 3] = -LOG2E * __expf(v.w);
  }
  __syncthreads();

  float h[NST];
#pragma unroll
  for (int n = 0; n < NST; ++n) h[n] = 0.f;
  float sdt = 0.f;

  const size_t base = ((size_t)b * LSEQ + l0) * DMODEL + tid;
  float dtc[4], uc[4];
#pragma unroll
  for (int j = 0; j < 4; ++j) {
    dtc[j] = delta[base + (size_t)j * DMODEL];
    uc[j] = xc[base + (size_t)j * DMODEL];
  }
  for (int lb = 0; lb < LC / 4; ++lb) {
    float dtn[4], un[4];
    if (lb < LC / 4 - 1) {
      size_t nb = base + (size_t)(lb * 4 + 4) * DMODEL;
#pragma unroll
      for (int j = 0; j < 4; ++j) {
        dtn[j] = delta[nb + (size_t)j * DMODEL];
        un[j] = xc[nb + (size_t)j * DMODEL];
      }
    }
#pragma unroll
    for (int j = 0; j < 4; ++j) {
      int l = lb * 4 + j;
      float dt = dtc[j];
      float dtu = dt * uc[j];
      sdt += dt;
      f32x4 B0 = *(const f32x4*)&Bsl[l][0];
      f32x4 B1 = *(const f32x4*)&Bsl[l][4];
      f32x4 B2 = *(const f32x4*)&Bsl[l][8];
      f32x4 B3 = *(const f32x4*)&Bsl[l][12];
      float Bv[NST] = {B0.x, B0.y, B0.z, B0.w, B1.x, B1.y, B1.z, B1.w,
                       B2.x, B2.y, B2.z, B2.w, B3.x, B3.y, B3.z, B3.w};
#pragma unroll
      for (int n = 0; n < NST; ++n) {
        float ab = __builtin_amdgcn_exp2f(dt * Aa2[n]);
        h[n] = fmaf(ab, h[n], dtu * Bv[n]);
      }
    }
#pragma unroll
    for (int j = 0; j < 4; ++j) {
      dtc[j] = dtn[j];
      uc[j] = un[j];
    }
  }

  const size_t ob = (((size_t)(b * NCHUNK + c)) * DMODEL + tid) * NST;
#pragma unroll
  for (int q = 0; q < 4; ++q) {
    float4 hv = {h[q * 4 + 0], h[q * 4 + 1], h[q * 4 + 2], h[q * 4 + 3]};
    *(float4*)(hout + ob + q * 4) = hv;
    float4 cv = {__builtin_amdgcn_exp2f(sdt * Aa2[q * 4 + 0]),
                 __builtin_amdgcn_exp2f(sdt * Aa2[q * 4 + 1]),
                 __builtin_amdgcn_exp2f(sdt * Aa2[q * 4 + 2]),
                 __builtin_amdgcn_exp2f(sdt * Aa2[q * 4 + 3])};
    *(float4*)(cumA + ob + q * 4) = cv;
  }
}

// ---------------------------------------------------------------------------
// Scan pass 2: sequential combine over chunks; one thread per (b,d,n).
// In-place: hstate holds h_out on entry, h_in (exclusive prefix) on exit.
// ---------------------------------------------------------------------------
__global__ __launch_bounds__(256) void scan_combine(
    float* __restrict__ hstate, const float* __restrict__ cumA) {
  const int t = blockIdx.x * 256 + threadIdx.x;
  const int n = t & (NST - 1);
  const int dd = (t / NST) & (DMODEL - 1);
  const int b = t / (NST * DMODEL);
  float h = 0.f;
  for (int c = 0; c < NCHUNK; ++c) {
    size_t idx = (((size_t)(b * NCHUNK + c)) * DMODEL + dd) * NST + n;
    float ho = hstate[c ? idx : idx];  // read h_out
    float ca = cumA[idx];
    hstate[idx] = h;                   // write h_in
    h = fmaf(ca, h, ho);
  }
}

// ---------------------------------------------------------------------------
// Scan pass 3: replay with correct h_in, y_pre = (y+xc*D)*silu(z) into zy.
// Register double-buffered unroll-4 l-loop.
// ---------------------------------------------------------------------------
__global__ __launch_bounds__(256) void scan_pass3(
    const float* __restrict__ delta, const float* __restrict__ xc,
    const float* __restrict__ bc, const float* __restrict__ A_log,
    const float* __restrict__ hin, const float* __restrict__ Dskip,
    float* __restrict__ zy) {
  __shared__ float BCs[LC][32];  // 8 KB
  const int tid = threadIdx.x;
  const int b = blockIdx.x / NCHUNK;
  const int c = blockIdx.x % NCHUNK;
  const int l0 = c * LC;

#pragma unroll
  for (int i = 0; i < 2; ++i) {  // LC*32 = 2048 floats = 512 float4
    int t = tid + i * 256;
    int r = t >> 3, q = t & 7;
    float4 v = *(const float4*)(bc + ((size_t)(b * LSEQ + l0 + r)) * 32 + q * 4);
    *(float4*)&BCs[r][q * 4] = v;
  }
  float Aa2[NST];
#pragma unroll
  for (int q = 0; q < 4; ++q) {
    float4 v = *(const float4*)(A_log + tid * NST + q * 4);
    Aa2[q * 4 + 0] = -LOG2E * __expf(v.x);
    Aa2[q * 4 + 1] = -LOG2E * __expf(v.y);
    Aa2[q * 4 + 2] = -LOG2E * __expf(v.z);
    Aa2[q * 4 + 3] = -LOG2E * __expf(v.w);
  }
  float h[NST];
  const size_t hb = (((size_t)(b * NCHUNK + c)) * DMODEL + tid) * NST;
#pragma unroll
  for (int q = 0; q < 4; ++q) {
    float4 v = *(const float4*)(hin + hb + q * 4);
    h[q * 4 + 0] = v.x;
    h[q * 4 + 1] = v.y;
    h[q * 4 + 2] = v.z;
    h[q * 4 + 3] = v.w;
  }
  const float dsk = Dskip[tid];
  __syncthreads();

  const size_t base = ((size_t)b * LSEQ + l0) * DMODEL + tid;
  float dtc[4], uc[4], zc[4];
#pragma unroll
  for (int j = 0; j < 4; ++j) {
    dtc[j] = delta[base + (size_t)j * DMODEL];
    uc[j] = xc[base + (size_t)j * DMODEL];
    zc[j] = zy[base + (size_t)j * DMODEL];
  }
  for (int lb = 0; lb < LC / 4; ++lb) {
    float dtn[4], un[4], zn[4];
    if (lb < LC / 4 - 1) {
      size_t nb = base + (size_t)(lb * 4 + 4) * DMODEL;
#pragma unroll
      for (int j = 0; j < 4; ++j) {
        dtn[j] = delta[nb + (size_t)j * DMODEL];
        un[j] = xc[nb + (size_t)j * DMODEL];
        zn[j] = zy[nb + (size_t)j * DMODEL];
      }
    }
#pragma unroll
    for (int j = 0; j < 4; ++j) {
      int l = lb * 4 + j;
      float dt = dtc[j];
      float u = uc[j];
      float dtu = dt * u;
      f32x4 B0 = *(const f32x4*)&BCs[l][0];
      f32x4 B1 = *(const f32x4*)&BCs[l][4];
      f32x4 B2 = *(const f32x4*)&BCs[l][8];
      f32x4 B3 = *(const f32x4*)&BCs[l][12];
      f32x4 C0 = *(const f32x4*)&BCs[l][16];
      f32x4 C1 = *(const f32x4*)&BCs[l][20];
      f32x4 C2 = *(const f32x4*)&BCs[l][24];
      f32x4 C3 = *(const f32x4*)&BCs[l][28];
      float Bv[NST] = {B0.x, B0.y, B0.z, B0.w, B1.x, B1.y, B1.z, B1.w,
                       B2.x, B2.y, B2.z, B2.w, B3.x, B3.y, B3.z, B3.w};
      float Cv[NST] = {C0.x, C0.y, C0.z, C0.w, C1.x, C1.y, C1.z, C1.w,
                       C2.x, C2.y, C2.z, C2.w, C3.x, C3.y, C3.z, C3.w};
      float y = 0.f;
#pragma unroll
      for (int n = 0; n < NST; ++n) {
        float ab = __builtin_amdgcn_exp2f(dt * Aa2[n]);
        h[n] = fmaf(ab, h[n], dtu * Bv[n]);
        y = fmaf(h[n], Cv[n], y);
      }
      size_t idx = base + (size_t)l * DMODEL;
      zy[idx] = (y + u * dsk) * silu_f(zc[j]);
    }
#pragma unroll
    for (int j = 0; j < 4; ++j) {
      dtc[j] = dtn[j];
      uc[j] = un[j];
      zc[j] = zn[j];
    }
  }
}

// ---------------------------------------------------------------------------
extern "C" void kernel_launch(void* const* d_in, const int* in_sizes, int n_in,
                              void* d_out, int out_size, void* d_ws,
                              size_t ws_size, hipStream_t stream) {
  const float* x       = (const float*)d_in[0];
  const float* A_log   = (const float*)d_in[1];
  const float* D_skip  = (const float*)d_in[2];
  const float* W_B     = (const float*)d_in[3];
  const float* W_C     = (const float*)d_in[4];
  const float* W_delta = (const float*)d_in[5];
  const float* b_delta = (const float*)d_in[6];
  const float* W_in    = (const float*)d_in[7];
  const float* b_in    = (const float*)d_in[8];
  const float* W_out   = (const float*)d_in[9];
  const float* b_out   = (const float*)d_in[10];
  const float* conv_w  = (const float*)d_in[11];
  const float* conv_b  = (const float*)d_in[12];

  float* ws = (float*)d_ws;
  const size_t MD = (size_t)MROWS * DMODEL;                 // 16.78M floats
  const size_t HP = (size_t)BATCH * NCHUNK * DMODEL * NST;  // 4.19M floats
  float* xin  = ws;        // x_in; reused as delta
  float* zy   = xin + MD;  // z; reused as y_pre
  float* xc   = zy + MD;
  float* bc   = xc + MD;   // [M,32]
  float* hst  = bc + (size_t)MROWS * 32;  // h_out, then h_in (in-place)
  float* cumA = hst + HP;
  // total ws: 3*MD + MROWS*32 + 2*HP = 60.8M floats = 243 MB

  mfma_main<0><<<dim3(2, MROWS / 128), 512, 0, stream>>>(x, W_in, b_in, xin, zy);
  conv_silu_k<<<dim3(BATCH * LSEQ / 4), 256, 0, stream>>>(xin, conv_w, conv_b, xc);
  mfma_main<1><<<dim3(1, MROWS / 128), 512, 0, stream>>>(xc, W_delta, b_delta, xin, nullptr);
  mfma_bc<<<dim3(1, MROWS / 256), 256, 0, stream>>>(xc, W_B, W_C, bc);
  scan_pass1<<<dim3(BATCH * NCHUNK), 256, 0, stream>>>(xin, xc, bc, A_log, hst, cumA);
  scan_combine<<<dim3(BATCH * DMODEL * NST / 256), 256, 0, stream>>>(hst, cumA);
  scan_pass3<<<dim3(BATCH * NCHUNK), 256, 0, stream>>>(xin, xc, bc, A_log, hst, D_skip, zy);
  mfma_main<3><<<dim3(1, MROWS / 128), 512, 0, stream>>>(zy, W_out, b_out, (float*)d_out, nullptr);
}

// Round 4
// 313.258 us; speedup vs baseline: 2.5152x; 1.0670x over previous
//
#include <hip/hip_runtime.h>
#include <hip/hip_bf16.h>
#include <math.h>

#define BATCH 16
#define LSEQ 4096
#define DMODEL 256
#define NST 16
#define LC 64
#define NCHUNK (LSEQ / LC)
#define MROWS (BATCH * LSEQ)
#define LOG2E 1.44269504088896340736f

typedef float f32x4 __attribute__((ext_vector_type(4)));
typedef short bf16x8 __attribute__((ext_vector_type(8)));

__device__ __forceinline__ float silu_f(float v) { return v / (1.f + __expf(-v)); }
__device__ __forceinline__ float softplus_f(float v) {
  return fmaxf(v, 0.f) + log1pf(__expf(-fabsf(v)));
}

// fp32 -> bf16 round-to-nearest-even (finite inputs), packed pair
__device__ __forceinline__ uint bf16rne(float f) {
  uint u = __float_as_uint(f);
  return (u + 0x7fffu + ((u >> 16) & 1u)) >> 16;
}
__device__ __forceinline__ uint pk2(float x, float y) {
  return bf16rne(x) | (bf16rne(y) << 16);
}
__device__ __forceinline__ uint4 pk8(float4 a, float4 b) {
  uint4 r;
  r.x = pk2(a.x, a.y);
  r.y = pk2(a.z, a.w);
  r.z = pk2(b.x, b.y);
  r.w = pk2(b.z, b.w);
  return r;
}

// async global(bf16)->LDS, 16 B per lane
__device__ __forceinline__ void glds16(const ushort* g, char* l) {
  __builtin_amdgcn_global_load_lds(
      (const __attribute__((address_space(1))) void*)g,
      (__attribute__((address_space(3))) void*)l, 16, 0, 0);
}

// ---------------------------------------------------------------------------
// Weight fp32->bf16 convert. dst layout (ushort offsets):
//   [0,131072) W_in | [131072,196608) W_delta | [196608,262144) W_out
//   [262144,266240) W_B | [266240,270336) W_C   (W_B/W_C = wbc[32][256])
// 132 blocks x 256 thr x 8 floats.
// ---------------------------------------------------------------------------
__global__ __launch_bounds__(256) void cvt_weights(
    const float* __restrict__ Win, const float* __restrict__ Wd,
    const float* __restrict__ Wo, const float* __restrict__ WB,
    const float* __restrict__ WC, ushort* __restrict__ dst) {
  size_t i = ((size_t)blockIdx.x * 256 + threadIdx.x) * 8;
  if (i >= 270336) return;
  const float* s;
  size_t o;
  if (i < 131072)      { s = Win; o = i; }
  else if (i < 196608) { s = Wd;  o = i - 131072; }
  else if (i < 262144) { s = Wo;  o = i - 196608; }
  else if (i < 266240) { s = WB;  o = i - 262144; }
  else                 { s = WC;  o = i - 266240; }
  float4 a = *(const float4*)(s + o);
  float4 b = *(const float4*)(s + o + 4);
  *(uint4*)(dst + i) = pk8(a, b);
}

// ---------------------------------------------------------------------------
// MFMA GEMM v2: out[M,N] = A[M,256] @ B[N,256]^T (+bias, per-MODE epilogue)
// Tile 64 x 256, 256 thr (4 waves, wave w -> cols w*64). BK=32, 8 K-steps.
// A: fp32, reg-staged + packed; B: bf16 weights via global_load_lds (async).
// Double-buffered LDS (2 x 20 KB), ONE barrier per K-step.
// LDS chunk swizzle s4(r) = (r + (r>>2)) & 3  ->  2-way (free) bank aliasing.
// MODE 0: N=512 via gridDim.x=2; col<256 -> out0 (x_in) else out1 (z)
// MODE 1: softplus -> out0 (delta);  MODE 3: plain -> out0
// ---------------------------------------------------------------------------
template <int MODE>
__global__ __launch_bounds__(256, 4) void gemm2(
    const float* __restrict__ A, const ushort* __restrict__ Bbf,
    const float* __restrict__ bias, float* __restrict__ out0,
    float* __restrict__ out1) {
  constexpr int KD = 256;
  __shared__ char smem[40960];  // buf stride 20480: A[64][4]u4 @0, B[256][4]u4 @4096
  const int tid = threadIdx.x;
  const int lane = tid & 63, wid = tid >> 6;

  const int M0 = blockIdx.y * 64;
  const int N0 = blockIdx.x * 256;

  // staging maps
  const int rA = tid >> 2, cA = tid & 3;
  const int sA = (rA + (rA >> 2)) & 3;
  const float* gA = A + (size_t)(M0 + rA) * KD + cA * 8;
  const int ldsAoff = rA * 64 + ((cA ^ sA) * 16);
  const ushort* gB = Bbf + (size_t)(N0 + rA) * KD + ((cA ^ sA) * 8);

  f32x4 acc[4][4];
#pragma unroll
  for (int i = 0; i < 4; ++i)
#pragma unroll
    for (int j = 0; j < 4; ++j) acc[i][j] = {0.f, 0.f, 0.f, 0.f};

  // prologue: stage k-step 0 into buf0
  {
    float4 a0 = *(const float4*)(gA);
    float4 a1 = *(const float4*)(gA + 4);
#pragma unroll
    for (int i = 0; i < 4; ++i)
      glds16(gB + (size_t)i * 64 * KD, smem + 4096 + i * 4096 + wid * 1024);
    *(uint4*)(smem + ldsAoff) = pk8(a0, a1);
  }
  __syncthreads();

  for (int step = 0; step < 8; ++step) {
    const int cur = step & 1;
    char* bufc = smem + cur * 20480;
    char* bufn = smem + (cur ^ 1) * 20480;
    float4 na0, na1;
    if (step < 7) {
      const int k0 = (step + 1) * 32;
      na0 = *(const float4*)(gA + k0);
      na1 = *(const float4*)(gA + k0 + 4);
#pragma unroll
      for (int i = 0; i < 4; ++i)
        glds16(gB + (size_t)i * 64 * KD + k0,
               bufn + 4096 + i * 4096 + wid * 1024);
    }
    bf16x8 af[4], bfr[4];
#pragma unroll
    for (int i = 0; i < 4; ++i) {
      int r = i * 16 + (lane & 15);
      int slot = (lane >> 4) ^ ((r + (r >> 2)) & 3);
      af[i] = *(const bf16x8*)(bufc + r * 64 + slot * 16);
    }
#pragma unroll
    for (int j = 0; j < 4; ++j) {
      int r = wid * 64 + j * 16 + (lane & 15);
      int slot = (lane >> 4) ^ ((r + (r >> 2)) & 3);
      bfr[j] = *(const bf16x8*)(bufc + 4096 + r * 64 + slot * 16);
    }
#pragma unroll
    for (int i = 0; i < 4; ++i)
#pragma unroll
      for (int j = 0; j < 4; ++j)
        acc[i][j] = __builtin_amdgcn_mfma_f32_16x16x32_bf16(af[i], bfr[j],
                                                            acc[i][j], 0, 0, 0);
    if (step < 7) *(uint4*)(bufn + ldsAoff) = pk8(na0, na1);
    __syncthreads();
  }

  // epilogue
  const int rbase = (lane >> 4) * 4;
  const int cn = lane & 15;
#pragma unroll
  for (int i = 0; i < 4; ++i) {
#pragma unroll
    for (int j = 0; j < 4; ++j) {
      int col = N0 + wid * 64 + j * 16 + cn;
      float bs = bias[col];
#pragma unroll
      for (int r = 0; r < 4; ++r) {
        int row = M0 + i * 16 + rbase + r;
        float v = acc[i][j][r] + bs;
        if constexpr (MODE == 1) v = softplus_f(v);
        if constexpr (MODE == 0) {
          if (col < DMODEL)
            out0[(size_t)row * DMODEL + col] = v;
          else
            out1[(size_t)row * DMODEL + (col - DMODEL)] = v;
        } else {
          out0[(size_t)row * DMODEL + col] = v;
        }
      }
    }
  }
}

// ---------------------------------------------------------------------------
// bc GEMM: out[M,32] = xc @ wbc[32,256]^T. Tile 128 x 32, 256 thr (4 waves,
// wave w -> rows w*32). B (16 KB bf16) staged ONCE via glds, swizzle
// c ^ (r&7); A fp32 reg-staged, dbuf. 8 K-steps, 4 MFMA/step/wave.
// ---------------------------------------------------------------------------
__global__ __launch_bounds__(256, 4) void gemm_bc2(
    const float* __restrict__ A, const ushort* __restrict__ wbc,
    float* __restrict__ out0) {
  constexpr int KD = 256;
  __shared__ char smem[32768];  // B[32][32]u4 @0 (16KB); A bufs @16384,@24576 ([128][4]u4)
  const int tid = threadIdx.x, lane = tid & 63, wid = tid >> 6;
  const int M0 = blockIdx.x * 128;

  {  // stage whole B once: issue i covers rows 8i..8i+7
    const int rB = tid >> 5, cB = tid & 31;
    const ushort* gB = wbc + (size_t)rB * KD + ((cB ^ (rB & 7)) * 8);
#pragma unroll
    for (int i = 0; i < 4; ++i)
      glds16(gB + (size_t)(8 * i) * KD, smem + (8 * i + 2 * wid) * 512);
  }

  const int rA = tid >> 2, cA = tid & 3;
  const int sA = (rA + (rA >> 2)) & 3;
  const float* gA = A + (size_t)(M0 + rA) * KD + cA * 8;  // half h: +64*KD
  const int ldsAoff = rA * 64 + ((cA ^ sA) * 16);         // half h: +4096

  f32x4 acc[2][2];
#pragma unroll
  for (int q = 0; q < 2; ++q)
#pragma unroll
    for (int j = 0; j < 2; ++j) acc[q][j] = {0.f, 0.f, 0.f, 0.f};

  {  // prologue A k-step 0 -> buf0
    float4 p0 = *(const float4*)(gA);
    float4 p1 = *(const float4*)(gA + 4);
    float4 p2 = *(const float4*)(gA + (size_t)64 * KD);
    float4 p3 = *(const float4*)(gA + (size_t)64 * KD + 4);
    *(uint4*)(smem + 16384 + ldsAoff) = pk8(p0, p1);
    *(uint4*)(smem + 16384 + 4096 + ldsAoff) = pk8(p2, p3);
  }
  __syncthreads();

  for (int step = 0; step < 8; ++step) {
    const int cur = step & 1;
    char* bufc = smem + 16384 + cur * 8192;
    char* bufn = smem + 16384 + (cur ^ 1) * 8192;
    float4 n0, n1, n2, n3;
    if (step < 7) {
      const int k0 = (step + 1) * 32;
      n0 = *(const float4*)(gA + k0);
      n1 = *(const float4*)(gA + k0 + 4);
      n2 = *(const float4*)(gA + (size_t)64 * KD + k0);
      n3 = *(const float4*)(gA + (size_t)64 * KD + k0 + 4);
    }
    bf16x8 af[2], bfr[2];
#pragma unroll
    for (int q = 0; q < 2; ++q) {
      int r = wid * 32 + q * 16 + (lane & 15);
      int slot = (lane >> 4) ^ ((r + (r >> 2)) & 3);
      af[q] = *(const bf16x8*)(bufc + r * 64 + slot * 16);
    }
#pragma unroll
    for (int j = 0; j < 2; ++j) {
      int r = j * 16 + (lane & 15);
      int ch = step * 4 + (lane >> 4);
      int slot = ch ^ (r & 7);
      bfr[j] = *(const bf16x8*)(smem + r * 512 + slot * 16);
    }
#pragma unroll
    for (int q = 0; q < 2; ++q)
#pragma unroll
      for (int j = 0; j < 2; ++j)
        acc[q][j] = __builtin_amdgcn_mfma_f32_16x16x32_bf16(af[q], bfr[j],
                                                            acc[q][j], 0, 0, 0);
    if (step < 7) {
      *(uint4*)(bufn + ldsAoff) = pk8(n0, n1);
      *(uint4*)(bufn + 4096 + ldsAoff) = pk8(n2, n3);
    }
    __syncthreads();
  }

  const int rbase = (lane >> 4) * 4, cn = lane & 15;
#pragma unroll
  for (int q = 0; q < 2; ++q)
#pragma unroll
    for (int j = 0; j < 2; ++j)
#pragma unroll
      for (int r = 0; r < 4; ++r) {
        int row = M0 + wid * 32 + q * 16 + rbase + r;
        out0[(size_t)row * 32 + j * 16 + cn] = acc[q][j][r];
      }
}

// ---------------------------------------------------------------------------
// Depthwise conv (k=3, pad=1) over time + bias + silu.
// ---------------------------------------------------------------------------
__global__ __launch_bounds__(256) void conv_silu_k(
    const float* __restrict__ xin, const float* __restrict__ conv_w,
    const float* __restrict__ conv_b, float* __restrict__ xc) {
  __shared__ float w0[DMODEL], w1[DMODEL], w2[DMODEL], cb[DMODEL];
  const int tid = threadIdx.x;
  w0[tid] = conv_w[tid * 3 + 0];
  w1[tid] = conv_w[tid * 3 + 1];
  w2[tid] = conv_w[tid * 3 + 2];
  cb[tid] = conv_b[tid];
  __syncthreads();

  const int blk = blockIdx.x;
  const int b = blk / (LSEQ / 4);
  const int lq = blk % (LSEQ / 4);
  const int l = lq * 4 + (tid >> 6);
  const int d4 = (tid & 63) * 4;
  const size_t base = ((size_t)b * LSEQ + l) * DMODEL + d4;

  float4 zf = {0.f, 0.f, 0.f, 0.f};
  float4 xm = (l > 0) ? *(const float4*)(xin + base - DMODEL) : zf;
  float4 x0 = *(const float4*)(xin + base);
  float4 xp = (l < LSEQ - 1) ? *(const float4*)(xin + base + DMODEL) : zf;

  float o0 = fmaf(w0[d4 + 0], xm.x, fmaf(w1[d4 + 0], x0.x, fmaf(w2[d4 + 0], xp.x, cb[d4 + 0])));
  float o1 = fmaf(w0[d4 + 1], xm.y, fmaf(w1[d4 + 1], x0.y, fmaf(w2[d4 + 1], xp.y, cb[d4 + 1])));
  float o2 = fmaf(w0[d4 + 2], xm.z, fmaf(w1[d4 + 2], x0.z, fmaf(w2[d4 + 2], xp.z, cb[d4 + 2])));
  float o3 = fmaf(w0[d4 + 3], xm.w, fmaf(w1[d4 + 3], x0.w, fmaf(w2[d4 + 3], xp.w, cb[d4 + 3])));
  float4 r = {silu_f(o0), silu_f(o1), silu_f(o2), silu_f(o3)};
  *(float4*)(xc + base) = r;
}

// ---------------------------------------------------------------------------
// Scan pass 1: per (b, chunk) block, 256 threads (one per d), LC=64.
// ---------------------------------------------------------------------------
__global__ __launch_bounds__(256) void scan_pass1(
    const float* __restrict__ delta, const float* __restrict__ xc,
    const float* __restrict__ bc, const float* __restrict__ A_log,
    float* __restrict__ hout, float* __restrict__ cumA) {
  __shared__ float Bsl[LC][NST];  // 4 KB
  const int tid = threadIdx.x;
  const int b = blockIdx.x / NCHUNK;
  const int c = blockIdx.x % NCHUNK;
  const int l0 = c * LC;

  {
    int r = tid >> 2, q = tid & 3;
    float4 v = *(const float4*)(bc + ((size_t)(b * LSEQ + l0 + r)) * 32 + q * 4);
    *(float4*)&Bsl[r][q * 4] = v;
  }
  float Aa2[NST];
#pragma unroll
  for (int q = 0; q < 4; ++q) {
    float4 v = *(const float4*)(A_log + tid * NST + q * 4);
    Aa2[q * 4 + 0] = -LOG2E * __expf(v.x);
    Aa2[q * 4 + 1] = -LOG2E * __expf(v.y);
    Aa2[q * 4 + 2] = -LOG2E * __expf(v.z);
    Aa2[q * 4 + 3] = -LOG2E * __expf(v.w);
  }
  __syncthreads();

  float h[NST];
#pragma unroll
  for (int n = 0; n < NST; ++n) h[n] = 0.f;
  float sdt = 0.f;

  const size_t base = ((size_t)b * LSEQ + l0) * DMODEL + tid;
  float dtc[4], uc[4];
#pragma unroll
  for (int j = 0; j < 4; ++j) {
    dtc[j] = delta[base + (size_t)j * DMODEL];
    uc[j] = xc[base + (size_t)j * DMODEL];
  }
  for (int lb = 0; lb < LC / 4; ++lb) {
    float dtn[4], un[4];
    if (lb < LC / 4 - 1) {
      size_t nb = base + (size_t)(lb * 4 + 4) * DMODEL;
#pragma unroll
      for (int j = 0; j < 4; ++j) {
        dtn[j] = delta[nb + (size_t)j * DMODEL];
        un[j] = xc[nb + (size_t)j * DMODEL];
      }
    }
#pragma unroll
    for (int j = 0; j < 4; ++j) {
      int l = lb * 4 + j;
      float dt = dtc[j];
      float dtu = dt * uc[j];
      sdt += dt;
      f32x4 B0 = *(const f32x4*)&Bsl[l][0];
      f32x4 B1 = *(const f32x4*)&Bsl[l][4];
      f32x4 B2 = *(const f32x4*)&Bsl[l][8];
      f32x4 B3 = *(const f32x4*)&Bsl[l][12];
      float Bv[NST] = {B0.x, B0.y, B0.z, B0.w, B1.x, B1.y, B1.z, B1.w,
                       B2.x, B2.y, B2.z, B2.w, B3.x, B3.y, B3.z, B3.w};
#pragma unroll
      for (int n = 0; n < NST; ++n) {
        float ab = __builtin_amdgcn_exp2f(dt * Aa2[n]);
        h[n] = fmaf(ab, h[n], dtu * Bv[n]);
      }
    }
#pragma unroll
    for (int j = 0; j < 4; ++j) {
      dtc[j] = dtn[j];
      uc[j] = un[j];
    }
  }

  const size_t ob = (((size_t)(b * NCHUNK + c)) * DMODEL + tid) * NST;
#pragma unroll
  for (int q = 0; q < 4; ++q) {
    float4 hv = {h[q * 4 + 0], h[q * 4 + 1], h[q * 4 + 2], h[q * 4 + 3]};
    *(float4*)(hout + ob + q * 4) = hv;
    float4 cv = {__builtin_amdgcn_exp2f(sdt * Aa2[q * 4 + 0]),
                 __builtin_amdgcn_exp2f(sdt * Aa2[q * 4 + 1]),
                 __builtin_amdgcn_exp2f(sdt * Aa2[q * 4 + 2]),
                 __builtin_amdgcn_exp2f(sdt * Aa2[q * 4 + 3])};
    *(float4*)(cumA + ob + q * 4) = cv;
  }
}

// ---------------------------------------------------------------------------
// Scan pass 2: sequential combine; in-place h_out -> h_in.
// ---------------------------------------------------------------------------
__global__ __launch_bounds__(256) void scan_combine(
    float* __restrict__ hstate, const float* __restrict__ cumA) {
  const int t = blockIdx.x * 256 + threadIdx.x;
  const int n = t & (NST - 1);
  const int dd = (t / NST) & (DMODEL - 1);
  const int b = t / (NST * DMODEL);
  float h = 0.f;
  for (int c = 0; c < NCHUNK; ++c) {
    size_t idx = (((size_t)(b * NCHUNK + c)) * DMODEL + dd) * NST + n;
    float ho = hstate[idx];
    float ca = cumA[idx];
    hstate[idx] = h;
    h = fmaf(ca, h, ho);
  }
}

// ---------------------------------------------------------------------------
// Scan pass 3: replay with h_in, y_pre = (y+xc*D)*silu(z) into zy.
// ---------------------------------------------------------------------------
__global__ __launch_bounds__(256) void scan_pass3(
    const float* __restrict__ delta, const float* __restrict__ xc,
    const float* __restrict__ bc, const float* __restrict__ A_log,
    const float* __restrict__ hin, const float* __restrict__ Dskip,
    float* __restrict__ zy) {
  __shared__ float BCs[LC][32];  // 8 KB
  const int tid = threadIdx.x;
  const int b = blockIdx.x / NCHUNK;
  const int c = blockIdx.x % NCHUNK;
  const int l0 = c * LC;

#pragma unroll
  for (int i = 0; i < 2; ++i) {
    int t = tid + i * 256;
    int r = t >> 3, q = t & 7;
    float4 v = *(const float4*)(bc + ((size_t)(b * LSEQ + l0 + r)) * 32 + q * 4);
    *(float4*)&BCs[r][q * 4] = v;
  }
  float Aa2[NST];
#pragma unroll
  for (int q = 0; q < 4; ++q) {
    float4 v = *(const float4*)(A_log + tid * NST + q * 4);
    Aa2[q * 4 + 0] = -LOG2E * __expf(v.x);
    Aa2[q * 4 + 1] = -LOG2E * __expf(v.y);
    Aa2[q * 4 + 2] = -LOG2E * __expf(v.z);
    Aa2[q * 4 + 3] = -LOG2E * __expf(v.w);
  }
  float h[NST];
  const size_t hb = (((size_t)(b * NCHUNK + c)) * DMODEL + tid) * NST;
#pragma unroll
  for (int q = 0; q < 4; ++q) {
    float4 v = *(const float4*)(hin + hb + q * 4);
    h[q * 4 + 0] = v.x;
    h[q * 4 + 1] = v.y;
    h[q * 4 + 2] = v.z;
    h[q * 4 + 3] = v.w;
  }
  const float dsk = Dskip[tid];
  __syncthreads();

  const size_t base = ((size_t)b * LSEQ + l0) * DMODEL + tid;
  float dtc[4], uc[4], zc[4];
#pragma unroll
  for (int j = 0; j < 4; ++j) {
    dtc[j] = delta[base + (size_t)j * DMODEL];
    uc[j] = xc[base + (size_t)j * DMODEL];
    zc[j] = zy[base + (size_t)j * DMODEL];
  }
  for (int lb = 0; lb < LC / 4; ++lb) {
    float dtn[4], un[4], zn[4];
    if (lb < LC / 4 - 1) {
      size_t nb = base + (size_t)(lb * 4 + 4) * DMODEL;
#pragma unroll
      for (int j = 0; j < 4; ++j) {
        dtn[j] = delta[nb + (size_t)j * DMODEL];
        un[j] = xc[nb + (size_t)j * DMODEL];
        zn[j] = zy[nb + (size_t)j * DMODEL];
      }
    }
#pragma unroll
    for (int j = 0; j < 4; ++j) {
      int l = lb * 4 + j;
      float dt = dtc[j];
      float u = uc[j];
      float dtu = dt * u;
      f32x4 B0 = *(const f32x4*)&BCs[l][0];
      f32x4 B1 = *(const f32x4*)&BCs[l][4];
      f32x4 B2 = *(const f32x4*)&BCs[l][8];
      f32x4 B3 = *(const f32x4*)&BCs[l][12];
      f32x4 C0 = *(const f32x4*)&BCs[l][16];
      f32x4 C1 = *(const f32x4*)&BCs[l][20];
      f32x4 C2 = *(const f32x4*)&BCs[l][24];
      f32x4 C3 = *(const f32x4*)&BCs[l][28];
      float Bv[NST] = {B0.x, B0.y, B0.z, B0.w, B1.x, B1.y, B1.z, B1.w,
                       B2.x, B2.y, B2.z, B2.w, B3.x, B3.y, B3.z, B3.w};
      float Cv[NST] = {C0.x, C0.y, C0.z, C0.w, C1.x, C1.y, C1.z, C1.w,
                       C2.x, C2.y, C2.z, C2.w, C3.x, C3.y, C3.z, C3.w};
      float y = 0.f;
#pragma unroll
      for (int n = 0; n < NST; ++n) {
        float ab = __builtin_amdgcn_exp2f(dt * Aa2[n]);
        h[n] = fmaf(ab, h[n], dtu * Bv[n]);
        y = fmaf(h[n], Cv[n], y);
      }
      size_t idx = base + (size_t)l * DMODEL;
      zy[idx] = (y + u * dsk) * silu_f(zc[j]);
    }
#pragma unroll
    for (int j = 0; j < 4; ++j) {
      dtc[j] = dtn[j];
      uc[j] = un[j];
      zc[j] = zn[j];
    }
  }
}

// ---------------------------------------------------------------------------
extern "C" void kernel_launch(void* const* d_in, const int* in_sizes, int n_in,
                              void* d_out, int out_size, void* d_ws,
                              size_t ws_size, hipStream_t stream) {
  const float* x       = (const float*)d_in[0];
  const float* A_log   = (const float*)d_in[1];
  const float* D_skip  = (const float*)d_in[2];
  const float* W_B     = (const float*)d_in[3];
  const float* W_C     = (const float*)d_in[4];
  const float* W_delta = (const float*)d_in[5];
  const float* b_delta = (const float*)d_in[6];
  const float* W_in    = (const float*)d_in[7];
  const float* b_in    = (const float*)d_in[8];
  const float* W_out   = (const float*)d_in[9];
  const float* b_out   = (const float*)d_in[10];
  const float* conv_w  = (const float*)d_in[11];
  const float* conv_b  = (const float*)d_in[12];

  float* ws = (float*)d_ws;
  const size_t MD = (size_t)MROWS * DMODEL;                 // 16.78M floats
  const size_t HP = (size_t)BATCH * NCHUNK * DMODEL * NST;  // 4.19M floats
  float* xin  = ws;        // x_in; reused as delta
  float* zy   = xin + MD;  // z; reused as y_pre
  float* xc   = zy + MD;
  float* bc   = xc + MD;   // [M,32]
  float* hst  = bc + (size_t)MROWS * 32;  // h_out -> h_in (in-place)
  float* cumA = hst + HP;
  ushort* wbf = (ushort*)(cumA + HP);     // bf16 weights, 270336 ushorts
  // total ws: 3*MD + MROWS*32 + 2*HP + 135168 fl = ~244 MB

  cvt_weights<<<dim3(132), 256, 0, stream>>>(W_in, W_delta, W_out, W_B, W_C, wbf);
  gemm2<0><<<dim3(2, MROWS / 64), 256, 0, stream>>>(x, wbf, b_in, xin, zy);
  conv_silu_k<<<dim3(BATCH * LSEQ / 4), 256, 0, stream>>>(xin, conv_w, conv_b, xc);
  gemm2<1><<<dim3(1, MROWS / 64), 256, 0, stream>>>(xc, wbf + 131072, b_delta, xin, nullptr);
  gemm_bc2<<<dim3(MROWS / 128), 256, 0, stream>>>(xc, wbf + 262144, bc);
  scan_pass1<<<dim3(BATCH * NCHUNK), 256, 0, stream>>>(xin, xc, bc, A_log, hst, cumA);
  scan_combine<<<dim3(BATCH * DMODEL * NST / 256), 256, 0, stream>>>(hst, cumA);
  scan_pass3<<<dim3(BATCH * NCHUNK), 256, 0, stream>>>(xin, xc, bc, A_log, hst, D_skip, zy);
  gemm2<3><<<dim3(1, MROWS / 64), 256, 0, stream>>>(zy, wbf + 196608, b_out, (float*)d_out, nullptr);
}